// Round 6
// baseline (255.348 us; speedup 1.0000x reference)
//
#include <hip/hip_runtime.h>
#include <stdint.h>

typedef unsigned short u16;
typedef __attribute__((ext_vector_type(8))) __bf16 bf16x8;
typedef __attribute__((ext_vector_type(4))) float f32x4;

__device__ __forceinline__ u16 f2bf(float f) {
  unsigned u = __float_as_uint(f);
  u += 0x7FFF + ((u >> 16) & 1);   // RNE
  return (u16)(u >> 16);
}

__device__ __forceinline__ float bf2f(u16 h) {
  return __uint_as_float(((unsigned)h) << 16);
}

__device__ __forceinline__ void llds16(const u16* g, u16* l) {
  __builtin_amdgcn_global_load_lds(
      (const __attribute__((address_space(1))) void*)g,
      (__attribute__((address_space(3))) void*)l, 16, 0, 0);
}

// ---------------------------------------------------------------------------
// fused cast fp32 -> bf16 for x | wq | wk | wv + zero lsum + zero job counter
// ---------------------------------------------------------------------------
__global__ __launch_bounds__(256) void cast_all(
    const float* __restrict__ x, const float* __restrict__ wq,
    const float* __restrict__ wk, const float* __restrict__ wv,
    u16* __restrict__ xb, u16* __restrict__ wb, float* __restrict__ lsum,
    int* __restrict__ cnt) {
  int i = blockIdx.x * 256 + threadIdx.x;
  if (i < 8192) lsum[i] = 0.f;        // softmax-denominator accumulator
  if (i == 0) cnt[0] = 0;             // scores job-queue counter (lives in out[0])
  const float* src; u16* dst; int off;
  if (i < 2097152)      { src = x;  dst = xb;            off = i; }
  else if (i < 2359296) { src = wq; dst = wb;            off = i - 2097152; }
  else if (i < 2621440) { src = wk; dst = wb + 1048576;  off = i - 2359296; }
  else                  { src = wv; dst = wb + 2097152;  off = i - 2621440; }
  float4 f = ((const float4*)src)[off];
  ushort4 o;
  o.x = f2bf(f.x); o.y = f2bf(f.y); o.z = f2bf(f.z); o.w = f2bf(f.w);
  ((ushort4*)dst)[off] = o;
}

// ---------------------------------------------------------------------------
// Shared NT GEMM core: C[M,N] = A[M,K] * B[N,K]^T  (row-major bf16, fp32 acc)
// 128x128 tile, BK=64, 256 threads = 4 waves (2x2), each wave 64x64 via 4x4
// mfma_f32_16x16x32_bf16, 2 k-steps/iter.  global_load_lds width-16 staging.
// LDS chunk-XOR swizzle: row r's 16B k-chunk c stored at slot c^(r&7) ->
// SQ_LDS_BANK_CONFLICT == 0 measured.  Do NOT switch to 32x32x16: its
// frag-read pattern re-conflicts under this swizzle.
// NOTE (rounds 1-2): a 256x256-tile 8-phase port ran SLOWER (626-700 TF vs
// 786 TF here): 1 block/CU -> grid quantizes to 2 rounds (75% util) and
// K=1024 too short to amortize the pipeline.  Keep 128^2 for this shape.
// NOTE (rounds 3-4): decode-permutation "XCD locality / pairing" tweaks
// based on an assumed block->CU dispatch model produced ZERO delta twice.
// NOTE (round 5): inlining this core into named wrappers pushed QKV's VGPR
// 80->116 (occupancy 26->19%, 65.6->68.7us).  Wrappers now carry explicit
// __launch_bounds__ caps to pin regalloc.
// MODE 0: QKV  -> cols <2048 to qk (bf16), cols >=2048 to vt transposed
// MODE 1: scores -> exp(s*scale) fused (|s| small, no max-subtraction),
//         causal -> 0, row-sums via atomicAdd into lsum
// MODE 2: PV -> fp32, * rcp(lsum[row]), causal K-truncation
// ---------------------------------------------------------------------------
template<int MODE>
__device__ __forceinline__ void gemm_core(
    int rt, int ct, int zb, int causal, u16* As, u16* Bs,
    const u16* __restrict__ A, long long sA, int lda,
    const u16* __restrict__ B, long long sB, int ldb,
    void* __restrict__ Cp, long long sC, int ldc,
    int K, u16* __restrict__ vt, float scale, float* __restrict__ lsum) {
  const int t = threadIdx.x;

  const int rowbase = rt * 128;
  const int colbase = ct * 128;
  const u16* Ab = A + (long long)zb * sA;
  const u16* Bb = B + (long long)zb * sB;

  // causal PV: P[i,k]=0 for k>i -> only need k < rowbase+128
  int Keff = K;
  if (MODE == 2 && causal) Keff = min(K, rowbase + 128);

  const int lane = t & 63;
  const int wv = t >> 6;
  const int wr = wv >> 1;
  const int wc = wv & 1;
  const int quad = lane >> 4;
  const int lr = lane & 15;

  f32x4 acc[4][4];
  const f32x4 zero = {0.f, 0.f, 0.f, 0.f};
#pragma unroll
  for (int i = 0; i < 4; ++i)
#pragma unroll
    for (int j = 0; j < 4; ++j) acc[i][j] = zero;

  {
    // staging: load i covers rows i*32+(t>>3); lane fetches global chunk
    // (t&7)^((t>>3)&7) of its row (row&7 == (t>>3)&7 since i*32%8==0) so
    // the lane-linear DMA write produces the slot = chunk^(row&7) layout.
    const int csw = (t & 7) ^ ((t >> 3) & 7);
    const u16* ga = Ab + (long long)(rowbase + (t >> 3)) * lda + csw * 8;
    const u16* gb = Bb + (long long)(colbase + (t >> 3)) * ldb + csw * 8;
    const long long ra = 32LL * lda, rb = 32LL * ldb;
    u16* la = As + t * 8;
    u16* lb = Bs + t * 8;

    // frag read: row = wr*64 + tm*16 + lr, chunk = quad + ks*4,
    // slot = chunk ^ (lr&7)  (row&7 == lr&7);  ks=1 toggles u16-offset 32
    const int m7 = lr & 7;
    const int a_base = (wr * 64 + lr) * 64 + ((quad ^ m7) * 8);
    const int b_base = (wc * 64 + lr) * 64 + ((quad ^ m7) * 8);

    for (int k0 = 0; k0 < Keff; k0 += 64) {
      __syncthreads();               // prior frag reads done before overwrite
#pragma unroll
      for (int i = 0; i < 4; ++i) {
        llds16(ga + k0 + i * ra, la + i * 2048);
        llds16(gb + k0 + i * rb, lb + i * 2048);
      }
      __syncthreads();               // compiler drains vmcnt before barrier
#pragma unroll
      for (int ks = 0; ks < 2; ++ks) {
        const int ko = ks ? 32 : 0;  // slot ^= 4  ->  u16 offset ^ 32
        bf16x8 af[4], bfv[4];
#pragma unroll
        for (int tm = 0; tm < 4; ++tm)
          af[tm] = *(const bf16x8*)(As + ((a_base + tm * 1024) ^ ko));
#pragma unroll
        for (int tn = 0; tn < 4; ++tn)
          bfv[tn] = *(const bf16x8*)(Bs + ((b_base + tn * 1024) ^ ko));
#pragma unroll
        for (int tm = 0; tm < 4; ++tm)
#pragma unroll
          for (int tn = 0; tn < 4; ++tn)
            acc[tm][tn] = __builtin_amdgcn_mfma_f32_16x16x32_bf16(
                af[tm], bfv[tn], acc[tm][tn], 0, 0, 0);
      }
    }
  }

  // ------------------------------ epilogue ------------------------------
  // C/D layout (m89/m91): col = lane&15, row = (lane>>4)*4 + reg
  if (MODE == 0 && colbase >= 2048) {
    // V block: write transposed to vt[b][e][s]; 4 regs = 4 consecutive s
#pragma unroll
    for (int tm = 0; tm < 4; ++tm) {
      int s0 = rowbase + wr * 64 + tm * 16 + quad * 4;
      int b = s0 >> 11;
      int sl = s0 & 2047;
#pragma unroll
      for (int tn = 0; tn < 4; ++tn) {
        int e = colbase - 2048 + wc * 64 + tn * 16 + lr;
        ushort4 o;
        o.x = f2bf(acc[tm][tn][0]);
        o.y = f2bf(acc[tm][tn][1]);
        o.z = f2bf(acc[tm][tn][2]);
        o.w = f2bf(acc[tm][tn][3]);
        *(ushort4*)(vt + ((long long)(b * 1024 + e)) * 2048 + sl) = o;
      }
    }
    return;
  }

#pragma unroll
  for (int tm = 0; tm < 4; ++tm) {
#pragma unroll
    for (int r = 0; r < 4; ++r) {
      const int grow = rowbase + wr * 64 + tm * 16 + quad * 4 + r;
      float li, rsum = 0.f;
      if (MODE == 2) li = __builtin_amdgcn_rcpf(lsum[zb * 2048 + grow]);
#pragma unroll
      for (int tn = 0; tn < 4; ++tn) {
        const int gcol = colbase + wc * 64 + tn * 16 + lr;
        float val = acc[tm][tn][r];
        if (MODE == 0) {
          ((u16*)Cp)[(long long)grow * ldc + gcol] = f2bf(val);
        } else if (MODE == 1) {
          u16* C = (u16*)Cp + (long long)zb * sC;
          float ex = (causal && gcol > grow) ? 0.f : __expf(val * scale);
          C[(long long)grow * ldc + gcol] = f2bf(ex);
          rsum += ex;
        } else {
          float* C = (float*)Cp + (long long)zb * sC;
          C[(long long)grow * ldc + gcol] = val * li;
        }
      }
      if (MODE == 1) {
        // reduce over the 16 col-lanes of this row (within the quad),
        // then one atomic per row-instance
#pragma unroll
        for (int o = 8; o > 0; o >>= 1) rsum += __shfl_xor(rsum, o, 64);
        if (lr == 0)
          atomicAdd(&lsum[zb * 2048 + grow], rsum);
      }
    }
  }
}

// ---------------------------------------------------------------------------
// QKV: [8192 x 3072] = xb @ wb^T ; Q,K -> qk, V -> vt (transposed).
// Launched as TWO half-dispatches (ct_off 0 / 12) so each runs ~33us and
// vacates the rocprof top-5 window -> sc/pv counters become visible.
// __launch_bounds__(256,6) pins VGPR <=85 (restores r4's 80-VGPR codegen).
// ---------------------------------------------------------------------------
__global__ __launch_bounds__(256, 6) void gemm_qkv(
    const u16* __restrict__ xb, const u16* __restrict__ wb,
    u16* __restrict__ qk, u16* __restrict__ vt, int ct_off) {
  __shared__ u16 As[8192];
  __shared__ u16 Bs[8192];
  gemm_core<0>(blockIdx.x, blockIdx.y + ct_off, 0, 1, As, Bs,
               xb, 0, 1024, wb, 0, 1024, qk, 0, 2048, 1024, vt, 1.0f, nullptr);
}

// ---------------------------------------------------------------------------
// scores: P' = exp((Q @ K^T)/32), causal -> lower-tri tiles only, bf16 out;
// row sums -> lsum via atomics.  DYNAMIC JOB QUEUE: 512 persistent blocks
// grab equal-size tile jobs via atomicAdd — balance guaranteed regardless
// of block->CU assignment.  Counter lives in out[0]: zeroed by cast_all,
// scores never writes out, PV overwrites it later; strictly ordered by
// kernel boundaries.
// ---------------------------------------------------------------------------
__global__ __launch_bounds__(256, 4) void gemm_sc(
    const u16* __restrict__ qk, u16* __restrict__ sb,
    float* __restrict__ lsum, const int* __restrict__ causalp,
    int* __restrict__ cnt) {
  __shared__ u16 As[8192];
  __shared__ u16 Bs[8192];
  __shared__ int jsh;
  const int causal = causalp[0];
  const int njobs = causal ? 544 : 1024;   // 4 * (136 lower-tri | 256 full)
  for (;;) {
    if (threadIdx.x == 0) jsh = atomicAdd(cnt, 1);
    __syncthreads();
    const int j = jsh;
    if (j >= njobs) return;
    int zb, rt, ct;
    if (causal) {
      zb = j / 136;
      int i2 = j - zb * 136, r = 0;
      while (i2 >= r + 1) { i2 -= r + 1; ++r; }   // row-major lower triangle
      rt = r; ct = i2;
    } else {
      zb = j >> 8;
      const int rem = j & 255;
      rt = rem >> 4; ct = rem & 15;
    }
    gemm_core<1>(rt, ct, zb, causal, As, Bs,
                 qk, 2048LL * 2048, 2048, qk + 1024, 2048LL * 2048, 2048,
                 sb, 2048LL * 2048, 2048, 1024, nullptr, 0.03125f, lsum);
    __syncthreads();   // all lanes done with jsh/LDS before next grab
  }
}

// ---------------------------------------------------------------------------
// PV: out[2048 x 1024] = (P' @ (V^T)^T) * rcp(lsum) per batch, fp32.
// Static longest-first decode (unchanged control from rounds 4-5).
// ---------------------------------------------------------------------------
__global__ __launch_bounds__(256, 4) void gemm_pv(
    const u16* __restrict__ sb, const u16* __restrict__ vtb,
    float* __restrict__ out, float* __restrict__ lsum,
    const int* __restrict__ causalp) {
  __shared__ u16 As[8192];
  __shared__ u16 Bs[8192];
  const int causal = causalp[0];
  const int s = ((blockIdx.x & 7) << 6) + (blockIdx.x >> 3);
  const int zb = s >> 7;
  const int ct = (s & 127) >> 4;
  const int m = s & 15;
  const int rt = (s & 32) ? m : 15 - m;
  gemm_core<2>(rt, ct, zb, causal, As, Bs,
               sb, 2048LL * 2048, 2048, vtb, 1024LL * 2048, 2048,
               out, 2048LL * 1024, 1024, 2048, nullptr, 1.0f, lsum);
}

// ---------------------------------------------------------------------------
extern "C" void kernel_launch(void* const* d_in, const int* in_sizes, int n_in,
                              void* d_out, int out_size, void* d_ws, size_t ws_size,
                              hipStream_t stream) {
  const float* x  = (const float*)d_in[0];
  const float* wq = (const float*)d_in[1];
  const float* wk = (const float*)d_in[2];
  const float* wv = (const float*)d_in[3];
  const int* causal = (const int*)d_in[4];
  float* out = (float*)d_out;

  // workspace layout (bytes):
  //   xb 0..16,777,216   wb ..23,068,672   qk ..56,623,104
  //   vt ..73,400,320    sb ..106,954,752  lsum ..106,987,520
  char* ws = (char*)d_ws;
  u16* xb = (u16*)(ws);               // [8192][1024] bf16 x
  u16* wb = (u16*)(ws + 16777216);    // [3072][1024] bf16 Wq|Wk|Wv
  u16* qk = (u16*)(ws + 23068672);    // [8192][2048] bf16 Q|K
  u16* vt = (u16*)(ws + 56623104);    // [4][1024][2048] bf16 V^T
  u16* sb = (u16*)(ws + 73400320);    // [4][2048][2048] bf16 exp-scores
  float* lsum = (float*)(ws + 106954752);  // [4][2048] softmax denominators
  int* cnt = (int*)out;               // scores job counter (see gemm_sc)

  // casts (x, wq, wk, wv -> bf16) + lsum/counter zero-init, one launch
  cast_all<<<11264, 256, 0, stream>>>(x, wq, wk, wv, xb, wb, lsum, cnt);

  // QKV: [8192 x 3072] = xb @ wb^T ; Q,K -> qk, V -> vt (transposed)
  // two half-dispatches (cols 0..1535 | 1536..3071) for rocprof visibility
  gemm_qkv<<<dim3(64, 12, 1), 256, 0, stream>>>(xb, wb, qk, vt, 0);
  gemm_qkv<<<dim3(64, 12, 1), 256, 0, stream>>>(xb, wb, qk, vt, 12);

  // exp-scores: dynamic queue, 512 persistent blocks
  gemm_sc<<<dim3(512, 1, 1), 256, 0, stream>>>(qk, sb, lsum, causal, cnt);

  // out per batch: [2048 x 1024] = (P' @ (V^T)^T) * rcp(lsum) -> fp32
  gemm_pv<<<dim3(512, 1, 1), 256, 0, stream>>>(sb, vt, out, lsum, causal);
}

// Round 7
// 230.000 us; speedup vs baseline: 1.1102x; 1.1102x over previous
//
#include <hip/hip_runtime.h>
#include <stdint.h>

typedef unsigned short u16;
typedef __attribute__((ext_vector_type(8))) __bf16 bf16x8;
typedef __attribute__((ext_vector_type(4))) float f32x4;

__device__ __forceinline__ u16 f2bf(float f) {
  unsigned u = __float_as_uint(f);
  u += 0x7FFF + ((u >> 16) & 1);   // RNE
  return (u16)(u >> 16);
}

__device__ __forceinline__ float bf2f(u16 h) {
  return __uint_as_float(((unsigned)h) << 16);
}

__device__ __forceinline__ void llds16(const u16* g, u16* l) {
  __builtin_amdgcn_global_load_lds(
      (const __attribute__((address_space(1))) void*)g,
      (__attribute__((address_space(3))) void*)l, 16, 0, 0);
}

// ---------------------------------------------------------------------------
// fused cast fp32 -> bf16 for x | wq | wk | wv + zero lsum + zero job counter
// ---------------------------------------------------------------------------
__global__ __launch_bounds__(256) void cast_all(
    const float* __restrict__ x, const float* __restrict__ wq,
    const float* __restrict__ wk, const float* __restrict__ wv,
    u16* __restrict__ xb, u16* __restrict__ wb, float* __restrict__ lsum,
    int* __restrict__ cnt) {
  int i = blockIdx.x * 256 + threadIdx.x;
  if (i < 8192) lsum[i] = 0.f;        // softmax-denominator accumulator
  if (i == 0) cnt[0] = 0;             // scores job-queue counter (in ws)
  const float* src; u16* dst; int off;
  if (i < 2097152)      { src = x;  dst = xb;            off = i; }
  else if (i < 2359296) { src = wq; dst = wb;            off = i - 2097152; }
  else if (i < 2621440) { src = wk; dst = wb + 1048576;  off = i - 2359296; }
  else                  { src = wv; dst = wb + 2097152;  off = i - 2621440; }
  float4 f = ((const float4*)src)[off];
  ushort4 o;
  o.x = f2bf(f.x); o.y = f2bf(f.y); o.z = f2bf(f.z); o.w = f2bf(f.w);
  ((ushort4*)dst)[off] = o;
}

// ---------------------------------------------------------------------------
// Shared NT GEMM core: C[M,N] = A[M,K] * B[N,K]^T  (row-major bf16, fp32 acc)
// 128x128 tile, BK=64, 256 threads = 4 waves (2x2), each wave 64x64 via 4x4
// mfma_f32_16x16x32_bf16, 2 k-steps/iter.  global_load_lds width-16 staging.
// LDS chunk-XOR swizzle: row r's 16B k-chunk c stored at slot c^(r&7) ->
// SQ_LDS_BANK_CONFLICT == 0 measured.
// DBUF=0: original single-buffer loop (stage -> barrier -> compute ->
//   barrier).  Right choice when >=4 blocks/CU co-resident (QKV: 1536-block
//   grid, ~5/CU) — inter-block overlap hides the drain (m114).
// DBUF=1: T3-minimum 2-phase double-buffer (round 6: sc measured MfmaUtil
//   10.6%, VALUBusy 8.3%, occupancy 13% = latency-bound at 2 blocks/CU;
//   drain exposed every K-step).  Loop: {prefetch buf^1 -> compute buf ->
//   __syncthreads}.  Plain-HIP-safe: compiler's vmcnt/lgkm drain before the
//   barrier IS the intended phase wait.  Hazards: RAW (read buf staged last
//   iter) covered by prev barrier's vmcnt(0); WAR (overwrite buf^1) covered
//   by lgkmcnt(0)+barrier after its reads.  LDS 64KB -> 2 blocks/CU (grid
//   gives only 2 anyway).
// NOTE history: r1-2 256^2/8-phase port SLOWER (grid quantization, short K).
//   r3-4 static decode permutations: zero delta twice.  r5 wrapper refactor
//   pushed QKV VGPR 80->116 (-3us).  r6 launch_bounds caps backfired
//   (spills); caps removed.
// MODE 0: QKV  -> cols <2048 to qk (bf16), cols >=2048 to vt transposed
// MODE 1: scores -> exp(s*scale) fused, causal -> 0, row-sums atomicAdd
// MODE 2: PV -> fp32, * rcp(lsum[row]), causal K-truncation
// ---------------------------------------------------------------------------
template<int MODE, int DBUF>
__device__ __forceinline__ void gemm_core(
    int rt, int ct, int zb, int causal, u16* As, u16* Bs,
    const u16* __restrict__ A, long long sA, int lda,
    const u16* __restrict__ B, long long sB, int ldb,
    void* __restrict__ Cp, long long sC, int ldc,
    int K, u16* __restrict__ vt, float scale, float* __restrict__ lsum) {
  const int t = threadIdx.x;

  const int rowbase = rt * 128;
  const int colbase = ct * 128;
  const u16* Ab = A + (long long)zb * sA;
  const u16* Bb = B + (long long)zb * sB;

  // causal PV: P[i,k]=0 for k>i -> only need k < rowbase+128
  int Keff = K;
  if (MODE == 2 && causal) Keff = min(K, rowbase + 128);

  const int lane = t & 63;
  const int wv = t >> 6;
  const int wr = wv >> 1;
  const int wc = wv & 1;
  const int quad = lane >> 4;
  const int lr = lane & 15;

  f32x4 acc[4][4];
  const f32x4 zero = {0.f, 0.f, 0.f, 0.f};
#pragma unroll
  for (int i = 0; i < 4; ++i)
#pragma unroll
    for (int j = 0; j < 4; ++j) acc[i][j] = zero;

  {
    // staging: load i covers rows i*32+(t>>3); lane fetches global chunk
    // (t&7)^((t>>3)&7) of its row (row&7 == (t>>3)&7 since i*32%8==0) so
    // the lane-linear DMA write produces the slot = chunk^(row&7) layout.
    const int csw = (t & 7) ^ ((t >> 3) & 7);
    const u16* ga = Ab + (long long)(rowbase + (t >> 3)) * lda + csw * 8;
    const u16* gb = Bb + (long long)(colbase + (t >> 3)) * ldb + csw * 8;
    const long long ra = 32LL * lda, rb = 32LL * ldb;
    u16* la = As + t * 8;
    u16* lb = Bs + t * 8;

    // frag read: row = wr*64 + tm*16 + lr, chunk = quad + ks*4,
    // slot = chunk ^ (lr&7)  (row&7 == lr&7);  ks=1 toggles u16-offset 32
    const int m7 = lr & 7;
    const int a_base = (wr * 64 + lr) * 64 + ((quad ^ m7) * 8);
    const int b_base = (wc * 64 + lr) * 64 + ((quad ^ m7) * 8);

    if (DBUF == 0) {
      for (int k0 = 0; k0 < Keff; k0 += 64) {
        __syncthreads();             // prior frag reads done before overwrite
#pragma unroll
        for (int i = 0; i < 4; ++i) {
          llds16(ga + k0 + i * ra, la + i * 2048);
          llds16(gb + k0 + i * rb, lb + i * 2048);
        }
        __syncthreads();             // compiler drains vmcnt before barrier
#pragma unroll
        for (int ks = 0; ks < 2; ++ks) {
          const int ko = ks ? 32 : 0;
          bf16x8 af[4], bfv[4];
#pragma unroll
          for (int tm = 0; tm < 4; ++tm)
            af[tm] = *(const bf16x8*)(As + ((a_base + tm * 1024) ^ ko));
#pragma unroll
          for (int tn = 0; tn < 4; ++tn)
            bfv[tn] = *(const bf16x8*)(Bs + ((b_base + tn * 1024) ^ ko));
#pragma unroll
          for (int tm = 0; tm < 4; ++tm)
#pragma unroll
            for (int tn = 0; tn < 4; ++tn)
              acc[tm][tn] = __builtin_amdgcn_mfma_f32_16x16x32_bf16(
                  af[tm], bfv[tn], acc[tm][tn], 0, 0, 0);
        }
      }
      __syncthreads();               // LDS safe for caller reuse (queue loop)
    } else {
      // ---- 2-phase double-buffered pipeline ----
#pragma unroll
      for (int i = 0; i < 4; ++i) {   // prologue: stage k=0 into buf0
        llds16(ga + i * ra, la + i * 2048);
        llds16(gb + i * rb, lb + i * 2048);
      }
      __syncthreads();
      for (int k0 = 0; k0 < Keff; k0 += 64) {
        const int nb = ((k0 >> 6) & 1) ^ 1;       // prefetch buffer
        const int bo = (nb ^ 1) << 13;            // current buffer offset
        if (k0 + 64 < Keff) {
#pragma unroll
          for (int i = 0; i < 4; ++i) {           // issue next-tile loads
            llds16(ga + (k0 + 64) + i * ra, la + nb * 8192 + i * 2048);
            llds16(gb + (k0 + 64) + i * rb, lb + nb * 8192 + i * 2048);
          }
        }
#pragma unroll
        for (int ks = 0; ks < 2; ++ks) {          // compute current buffer
          const int ko = ks ? 32 : 0;
          bf16x8 af[4], bfv[4];
#pragma unroll
          for (int tm = 0; tm < 4; ++tm)
            af[tm] = *(const bf16x8*)(As + bo + ((a_base + tm * 1024) ^ ko));
#pragma unroll
          for (int tn = 0; tn < 4; ++tn)
            bfv[tn] = *(const bf16x8*)(Bs + bo + ((b_base + tn * 1024) ^ ko));
#pragma unroll
          for (int tm = 0; tm < 4; ++tm)
#pragma unroll
            for (int tn = 0; tn < 4; ++tn)
              acc[tm][tn] = __builtin_amdgcn_mfma_f32_16x16x32_bf16(
                  af[tm], bfv[tn], acc[tm][tn], 0, 0, 0);
        }
        __syncthreads();   // drains prefetch (vmcnt0) + orders buffer reuse
      }
    }
  }

  // ------------------------------ epilogue ------------------------------
  // C/D layout (m89/m91): col = lane&15, row = (lane>>4)*4 + reg
  if (MODE == 0 && colbase >= 2048) {
    // V block: write transposed to vt[b][e][s]; 4 regs = 4 consecutive s
#pragma unroll
    for (int tm = 0; tm < 4; ++tm) {
      int s0 = rowbase + wr * 64 + tm * 16 + quad * 4;
      int b = s0 >> 11;
      int sl = s0 & 2047;
#pragma unroll
      for (int tn = 0; tn < 4; ++tn) {
        int e = colbase - 2048 + wc * 64 + tn * 16 + lr;
        ushort4 o;
        o.x = f2bf(acc[tm][tn][0]);
        o.y = f2bf(acc[tm][tn][1]);
        o.z = f2bf(acc[tm][tn][2]);
        o.w = f2bf(acc[tm][tn][3]);
        *(ushort4*)(vt + ((long long)(b * 1024 + e)) * 2048 + sl) = o;
      }
    }
    return;
  }

#pragma unroll
  for (int tm = 0; tm < 4; ++tm) {
#pragma unroll
    for (int r = 0; r < 4; ++r) {
      const int grow = rowbase + wr * 64 + tm * 16 + quad * 4 + r;
      float li, rsum = 0.f;
      if (MODE == 2) li = __builtin_amdgcn_rcpf(lsum[zb * 2048 + grow]);
#pragma unroll
      for (int tn = 0; tn < 4; ++tn) {
        const int gcol = colbase + wc * 64 + tn * 16 + lr;
        float val = acc[tm][tn][r];
        if (MODE == 0) {
          ((u16*)Cp)[(long long)grow * ldc + gcol] = f2bf(val);
        } else if (MODE == 1) {
          u16* C = (u16*)Cp + (long long)zb * sC;
          float ex = (causal && gcol > grow) ? 0.f : __expf(val * scale);
          C[(long long)grow * ldc + gcol] = f2bf(ex);
          rsum += ex;
        } else {
          float* C = (float*)Cp + (long long)zb * sC;
          C[(long long)grow * ldc + gcol] = val * li;
        }
      }
      if (MODE == 1) {
        // reduce over the 16 col-lanes of this row (within the quad),
        // then one atomic per row-instance
#pragma unroll
        for (int o = 8; o > 0; o >>= 1) rsum += __shfl_xor(rsum, o, 64);
        if (lr == 0)
          atomicAdd(&lsum[zb * 2048 + grow], rsum);
      }
    }
  }
}

// ---------------------------------------------------------------------------
// QKV: [8192 x 3072] = xb @ wb^T ; Q,K -> qk, V -> vt (transposed).
// Single dispatch (r6 half-split + launch_bounds caps regressed; reverted).
// Single-buffer core: 1536 blocks ~5/CU give inter-block overlap.
// ---------------------------------------------------------------------------
__global__ __launch_bounds__(256) void gemm_qkv(
    const u16* __restrict__ xb, const u16* __restrict__ wb,
    u16* __restrict__ qk, u16* __restrict__ vt) {
  __shared__ u16 As[8192];
  __shared__ u16 Bs[8192];
  gemm_core<0, 0>(blockIdx.x, blockIdx.y, 0, 1, As, Bs,
                  xb, 0, 1024, wb, 0, 1024, qk, 0, 2048, 1024, vt,
                  1.0f, nullptr);
}

// ---------------------------------------------------------------------------
// scores: P' = exp((Q @ K^T)/32), causal -> lower-tri tiles only, bf16 out;
// row sums -> lsum via atomics.  Dynamic job queue (512 persistent blocks,
// atomicAdd on a ws counter) + double-buffered core (DBUF=1).
// ---------------------------------------------------------------------------
__global__ __launch_bounds__(256) void gemm_sc(
    const u16* __restrict__ qk, u16* __restrict__ sb,
    float* __restrict__ lsum, const int* __restrict__ causalp,
    int* __restrict__ cnt) {
  __shared__ u16 As[16384];
  __shared__ u16 Bs[16384];
  __shared__ int jsh;
  const int causal = causalp[0];
  const int njobs = causal ? 544 : 1024;   // 4 * (136 lower-tri | 256 full)
  for (;;) {
    if (threadIdx.x == 0) jsh = atomicAdd(cnt, 1);
    __syncthreads();
    const int j = jsh;
    if (j >= njobs) return;
    int zb, rt, ct;
    if (causal) {
      zb = j / 136;
      int i2 = j - zb * 136, r = 0;
      while (i2 >= r + 1) { i2 -= r + 1; ++r; }   // row-major lower triangle
      rt = r; ct = i2;
    } else {
      zb = j >> 8;
      const int rem = j & 255;
      rt = rem >> 4; ct = rem & 15;
    }
    gemm_core<1, 1>(rt, ct, zb, causal, As, Bs,
                    qk, 2048LL * 2048, 2048, qk + 1024, 2048LL * 2048, 2048,
                    sb, 2048LL * 2048, 2048, 1024, nullptr, 0.03125f, lsum);
    __syncthreads();   // all lanes done with jsh/LDS before next grab
  }
}

// ---------------------------------------------------------------------------
// PV: out[2048 x 1024] = (P' @ (V^T)^T) * rcp(lsum) per batch, fp32.
// Static balanced decode (CU pair gets complementary Keff) + DBUF=1 core.
// ---------------------------------------------------------------------------
__global__ __launch_bounds__(256) void gemm_pv(
    const u16* __restrict__ sb, const u16* __restrict__ vtb,
    float* __restrict__ out, float* __restrict__ lsum,
    const int* __restrict__ causalp) {
  __shared__ u16 As[16384];
  __shared__ u16 Bs[16384];
  const int causal = causalp[0];
  const int s = ((blockIdx.x & 7) << 6) + (blockIdx.x >> 3);
  const int zb = s >> 7;
  const int ct = (s & 127) >> 4;
  const int m = s & 15;
  const int rt = (s & 32) ? m : 15 - m;
  gemm_core<2, 1>(rt, ct, zb, causal, As, Bs,
                  sb, 2048LL * 2048, 2048, vtb, 1024LL * 2048, 2048,
                  out, 2048LL * 1024, 1024, 2048, nullptr, 1.0f, lsum);
}

// ---------------------------------------------------------------------------
extern "C" void kernel_launch(void* const* d_in, const int* in_sizes, int n_in,
                              void* d_out, int out_size, void* d_ws, size_t ws_size,
                              hipStream_t stream) {
  const float* x  = (const float*)d_in[0];
  const float* wq = (const float*)d_in[1];
  const float* wk = (const float*)d_in[2];
  const float* wv = (const float*)d_in[3];
  const int* causal = (const int*)d_in[4];
  float* out = (float*)d_out;

  // workspace layout (bytes):
  //   xb 0..16,777,216   wb ..23,068,672   qk ..56,623,104
  //   vt ..73,400,320    sb ..106,954,752  lsum ..106,987,520  cnt ..+64
  char* ws = (char*)d_ws;
  u16* xb = (u16*)(ws);               // [8192][1024] bf16 x
  u16* wb = (u16*)(ws + 16777216);    // [3072][1024] bf16 Wq|Wk|Wv
  u16* qk = (u16*)(ws + 23068672);    // [8192][2048] bf16 Q|K
  u16* vt = (u16*)(ws + 56623104);    // [4][1024][2048] bf16 V^T
  u16* sb = (u16*)(ws + 73400320);    // [4][2048][2048] bf16 exp-scores
  float* lsum = (float*)(ws + 106954752);  // [4][2048] softmax denominators
  int* cnt = (int*)(ws + 106987520);  // scores job counter

  // casts (x, wq, wk, wv -> bf16) + lsum/counter zero-init, one launch
  cast_all<<<11264, 256, 0, stream>>>(x, wq, wk, wv, xb, wb, lsum, cnt);

  // QKV: [8192 x 3072] = xb @ wb^T ; Q,K -> qk, V -> vt (transposed)
  gemm_qkv<<<dim3(64, 24, 1), 256, 0, stream>>>(xb, wb, qk, vt);

  // exp-scores: dynamic queue, 512 persistent blocks, double-buffered
  gemm_sc<<<dim3(512, 1, 1), 256, 0, stream>>>(qk, sb, lsum, causal, cnt);

  // out per batch: [2048 x 1024] = (P' @ (V^T)^T) * rcp(lsum) -> fp32
  gemm_pv<<<dim3(512, 1, 1), 256, 0, stream>>>(sb, vt, out, lsum, causal);
}